// Round 5
// baseline (55.891 us; speedup 1.0000x reference)
//
#include <hip/hip_runtime.h>
#include <hip/hip_bf16.h>

typedef __bf16 bf16x8 __attribute__((ext_vector_type(8)));
typedef float  f32x4  __attribute__((ext_vector_type(4)));

#define NTILES      16384          // 262144 rows / 16
#define GEMM_BLOCKS 2048           // x 8 waves = 16384 waves -> exactly 1 tile/wave

// ---------------------------------------------------------------------------
// Kernel 1 (one-shot, 64 blocks): expand quaternion weight (32,32,4) ->
// W_eff (128x128) in bf16, in MFMA A-fragment order with the k-axis PERMUTED
// so the main kernel's x loads are full-granule coalesced:
//   element j of fragment (nt,kb,lane) holds physical
//     k = kb*32 + (j<4 ? g*4+j : 16 + g*4 + (j-4)),  g = lane>>4
// Same permutation on both MFMA operands -> identical math (verified r1-r4).
// ---------------------------------------------------------------------------
__global__ __launch_bounds__(256) void prep_wfrag(const float* __restrict__ w,
                                                  ushort* __restrict__ wfrag) {
    int t = blockIdx.x * 256 + threadIdx.x;   // fragment-element index
    if (t >= 128 * 128) return;
    int j    = t & 7;
    int lane = (t >> 3) & 63;
    int kb   = (t >> 9) & 3;
    int nt   = t >> 11;
    int g    = lane >> 4;
    int n = nt * 16 + (lane & 15);                                 // output feature
    int k = kb * 32 + (j < 4 ? g * 4 + j : 16 + g * 4 + (j - 4));  // input feature
    int o  = n >> 2, c = n & 3;
    int nq = k >> 2, d = k & 3;
    int comp = c ^ d;
    bool neg = (d != 0) && ((c == 0) || (c != d && d != (c % 3) + 1));
    float val = w[o * 128 + nq * 4 + comp];
    val = neg ? -val : val;
    __bf16 bv = (__bf16)val;
    wfrag[t] = *reinterpret_cast<ushort*>(&bv);
}

// ---------------------------------------------------------------------------
// Kernel 2: out = x @ W_eff^T + bias.  One 16-row tile per wave, fully flat:
// issue W-copy loads, issue x loads, LDS-write W (partial vmcnt), barrier,
// cvt, 32x{ds_read_b128 + MFMA}, 8x dwordx4 store, exit.  Latency hiding
// comes from 32 waves/CU of TLP, not in-wave looping.
// ---------------------------------------------------------------------------
__global__ __launch_bounds__(512, 8) void qgemm(const float* __restrict__ x,
                                                const ushort* __restrict__ wfrag,
                                                const float* __restrict__ bias,
                                                float* __restrict__ out) {
    __shared__ __align__(16) ushort wlds[16384];   // 32 KB fragment-ordered W
    __shared__ __align__(16) float  sbias[128];

    int tid   = threadIdx.x;
    int lane  = tid & 63;
    int wid   = tid >> 6;      // 0..7
    int row16 = lane & 15;     // batch row within tile == D col
    int kgrp  = lane >> 4;     // 0..3

    // 1) W-copy loads FIRST in vmcnt order: the ds_write below then only
    //    needs a partial vmcnt wait; the x loads stay in flight through it.
    int4 wtmp[4];
    {
        const int4* src = (const int4*)wfrag;
#pragma unroll
        for (int i = 0; i < 4; ++i) wtmp[i] = src[tid + i * 512];
    }

    // 2) x loads for this wave's tile (8 x dwordx4, full-granule coalesced
    //    thanks to the k-permutation baked into the W fragments).
    size_t tile = (size_t)blockIdx.x * 8 + wid;    // 0..16383
    const float4* xv = (const float4*)(x + tile * 2048 + row16 * 128);
    float4 r[8];
#pragma unroll
    for (int kb = 0; kb < 4; ++kb) {
        r[2 * kb]     = xv[kb * 8 + kgrp];
        r[2 * kb + 1] = xv[kb * 8 + kgrp + 4];
    }

    // 3) W -> LDS, bias -> LDS, barrier.
    {
        int4* dst = (int4*)wlds;
#pragma unroll
        for (int i = 0; i < 4; ++i) dst[tid + i * 512] = wtmp[i];
    }
    if (tid < 128) sbias[tid] = bias[tid];
    __syncthreads();

    // 4) cvt x -> bf16 fragments (loads have arrived by now).
    bf16x8 afr[4];
#pragma unroll
    for (int kb = 0; kb < 4; ++kb) {
        float4 p = r[2 * kb], q = r[2 * kb + 1];
        afr[kb][0] = (__bf16)p.x; afr[kb][1] = (__bf16)p.y;
        afr[kb][2] = (__bf16)p.z; afr[kb][3] = (__bf16)p.w;
        afr[kb][4] = (__bf16)q.x; afr[kb][5] = (__bf16)q.y;
        afr[kb][6] = (__bf16)q.z; afr[kb][7] = (__bf16)q.w;
    }

    // 5) MFMA + store.  D layout: col = lane&15 = batch row,
    //    row = kgrp*4 + r = feature -> lane stores float4 of consecutive
    //    features; 4 lanes fully cover each 64B granule.
    const bf16x8* blds = (const bf16x8*)wlds;
    float* op = out + tile * 2048 + row16 * 128 + kgrp * 4;
#pragma unroll
    for (int nt = 0; nt < 8; ++nt) {
        f32x4 acc = *(const f32x4*)&sbias[nt * 16 + kgrp * 4];
#pragma unroll
        for (int kb = 0; kb < 4; ++kb) {
            bf16x8 wfr = blds[(nt * 4 + kb) * 64 + lane];
            acc = __builtin_amdgcn_mfma_f32_16x16x32_bf16(wfr, afr[kb], acc, 0, 0, 0);
        }
        *(f32x4*)(op + nt * 16) = acc;
    }
}

extern "C" void kernel_launch(void* const* d_in, const int* in_sizes, int n_in,
                              void* d_out, int out_size, void* d_ws, size_t ws_size,
                              hipStream_t stream) {
    const float* x      = (const float*)d_in[0];   // [262144,128] fp32
    const float* weight = (const float*)d_in[1];   // [32,32,4] fp32
    const float* bias   = (const float*)d_in[2];   // [128] fp32
    float*       out    = (float*)d_out;           // [262144,128] fp32
    ushort*      wfrag  = (ushort*)d_ws;           // 32 KB fragment-ordered W_eff

    prep_wfrag<<<64, 256, 0, stream>>>(weight, wfrag);
    qgemm<<<GEMM_BLOCKS, 512, 0, stream>>>(x, wfrag, bias, out);
}